// Round 5
// baseline (151.228 us; speedup 1.0000x reference)
//
#include <hip/hip_runtime.h>
#include <hip/hip_bf16.h>

// Masked SDPA, flash-attention, transposed form (S^T = K*Q^T, O^T = V^T*P^T).
// R5: NO LDS staging for K/V. A fused prep kernel writes K-hat/V-hat (bf16) in
// MFMA-fragment order, so each fragment is ONE coalesced global_load_dwordx4
// (L2-resident: 2 MB per batch, XCD-swizzled). The K-loop has ZERO barriers:
// each of the 8 waves owns a private 512-key range (2 q-groups x 4 kv-slices)
// with independent online softmax; partials merge once at the end via LDS.
// P C-layout -> B-layout via small per-wave LDS buffer (pitch 112 B, b128
// conflict-free). Grid 256 x 512 thr.

#define BZ 8
#define QL 2048
#define KLEN 2048
#define DH 128
#define TOTROWS (BZ * QL)
#define NSL 64          // 32-key slices per batch
#define SLICE_E 4096    // elems per slice per tensor: 512 chunks x 8 bf16

typedef float f32x4 __attribute__((ext_vector_type(4)));
typedef int   i32x4 __attribute__((ext_vector_type(4)));
typedef __bf16 bf16x8 __attribute__((ext_vector_type(8)));
typedef __bf16 bf16x2 __attribute__((ext_vector_type(2)));

#define QSC 0.12751879523298232f  // SCALE * log2(e); softmax in exp2 units
#define NEGV -1000000000.0f
#define PPW 56  // P-buffer row pitch in bf16 (112 B = 7 x 16B): b128 reads conflict-free

// ---------------------------------------------------------------------------
// Fused prep: blocks 0..511 build K-hat, 512..1023 build V-hat. blk&511 = b*64+s.
// K-hat chunk (kf*2+f)*64 + ln  holds K[s*32 + f*16 + lc][kf*32 + qd*8 + j] j=0..7
// V-hat chunk  nt*64 + ln      holds V[s*32 + qd*8 + j][nt*16 + lc]        j=0..7
// (ln = qd*16+lc) -> every main-kernel fragment load is 64 lanes x contiguous 16B.
// ---------------------------------------------------------------------------
__global__ void prep_kv(const float* __restrict__ kg, const float* __restrict__ vg,
                        __bf16* __restrict__ khat, __bf16* __restrict__ vhat) {
  const int blk = blockIdx.x;
  const int bs = blk & 511;
  const int b = bs >> 6, s = bs & 63;
  const int tid = threadIdx.x;
#pragma unroll
  for (int i = 0; i < 2; ++i) {
    const int c = i * 256 + tid;          // chunk 0..511
    const int ln = c & 63, lc = ln & 15, qd = ln >> 4;
    if (blk < 512) {
      const int ff = (c >> 6) & 1, kf = c >> 7;
      const int key = s * 32 + ff * 16 + lc;
      const float* src = kg + ((size_t)(b * KLEN + key)) * DH + kf * 32 + qd * 8;
      f32x4 a = *(const f32x4*)src;
      f32x4 d = *(const f32x4*)(src + 4);
      bf16x8 w;
      w[0]=(__bf16)a[0]; w[1]=(__bf16)a[1]; w[2]=(__bf16)a[2]; w[3]=(__bf16)a[3];
      w[4]=(__bf16)d[0]; w[5]=(__bf16)d[1]; w[6]=(__bf16)d[2]; w[7]=(__bf16)d[3];
      *(bf16x8*)&khat[((size_t)bs * 512 + c) * 8] = w;
    } else {
      const int nt = c >> 6;
      const float* src = vg + ((size_t)(b * KLEN + s * 32 + qd * 8)) * DH + nt * 16 + lc;
      bf16x8 w;
#pragma unroll
      for (int j = 0; j < 8; ++j) w[j] = (__bf16)src[(size_t)j * DH];
      *(bf16x8*)&vhat[((size_t)bs * 512 + c) * 8] = w;
    }
  }
}

// ---------------------------------------------------------------------------
// Main kernel. Grid 256 (b = bid&7 -> XCD L2 locality; qt = bid>>3), 512 thr.
// Wave wv: qg = wv&1 (32 q-rows), sl = wv>>1 (512-key range, 16 iters x 32 keys).
// ---------------------------------------------------------------------------
__global__ __launch_bounds__(512, 2) void fattn3(
    const __bf16* __restrict__ khat, const __bf16* __restrict__ vhat,
    const float* __restrict__ qg_, const int* __restrict__ maskg,
    float* __restrict__ outg) {
  __shared__ __align__(16) unsigned char smem[33792];
  // loop phase:  sP = per-wave P buffers  [8 waves][2 qfl][16 rows][PPW bf16]
  // merge phase: mO = f32x4[2048] (32 KB) + sml floats (aliased after barrier B0)
  __bf16* sPall = (__bf16*)smem;
  f32x4* mO = (f32x4*)smem;
  float* sml = (float*)(smem + 32768);

  const int tid = threadIdx.x;
  const int wv = tid >> 6, ln = tid & 63;
  const int qd = ln >> 4, lc = ln & 15;
  const int b = blockIdx.x & 7, qt = blockIdx.x >> 3;
  const int q0 = qt * 64;
  const int qg = wv & 1, sl = wv >> 1;

  // ---- Q fragments (B-operand), resident: 2 qfl x 4 ksteps, pre-scaled ----
  bf16x8 qf[2][4];
#pragma unroll
  for (int qfl = 0; qfl < 2; ++qfl) {
    const float* qr = qg_ + ((size_t)(b * QL + q0 + qg * 32 + qfl * 16 + lc)) * DH + qd * 8;
#pragma unroll
    for (int kf = 0; kf < 4; ++kf) {
      f32x4 a = *(const f32x4*)(qr + kf * 32);
      f32x4 c = *(const f32x4*)(qr + kf * 32 + 4);
      bf16x8 t;
      t[0]=(__bf16)(a[0]*QSC); t[1]=(__bf16)(a[1]*QSC); t[2]=(__bf16)(a[2]*QSC); t[3]=(__bf16)(a[3]*QSC);
      t[4]=(__bf16)(c[0]*QSC); t[5]=(__bf16)(c[1]*QSC); t[6]=(__bf16)(c[2]*QSC); t[7]=(__bf16)(c[3]*QSC);
      qf[qfl][kf] = t;
    }
  }

  const __bf16* Kb = khat + (size_t)b * NSL * SLICE_E;
  const __bf16* Vb = vhat + (size_t)b * NSL * SLICE_E;
  const int* mrow = maskg + b * KLEN;
  __bf16* sP0 = sPall + (size_t)(wv * 2 + 0) * 16 * PPW;
  __bf16* sP1 = sPall + (size_t)(wv * 2 + 1) * 16 * PPW;

  f32x4 oacc[2][8];
#pragma unroll
  for (int qfl = 0; qfl < 2; ++qfl)
#pragma unroll
    for (int nt = 0; nt < 8; ++nt) oacc[qfl][nt] = (f32x4){0.f, 0.f, 0.f, 0.f};
  float mi[2] = {-INFINITY, -INFINITY}, li[2] = {0.f, 0.f};

  for (int it = 0; it < 16; ++it) {
    const int s = sl * 16 + it;
    const __bf16* ks = Kb + (size_t)s * SLICE_E;
    const __bf16* vs = Vb + (size_t)s * SLICE_E;
    const int kb0 = s * 32;

    // masks for this 32-key slice (C rows: key = kb0 + f*16 + qd*4 + r)
    i32x4 mk0 = *(const i32x4*)&mrow[kb0 + qd * 4];
    i32x4 mk1 = *(const i32x4*)&mrow[kb0 + 16 + qd * 4];

    // ---- K fragments: 8 coalesced 16B loads ----
    bf16x8 kA[4][2];
#pragma unroll
    for (int kf = 0; kf < 4; ++kf)
#pragma unroll
      for (int f = 0; f < 2; ++f)
        kA[kf][f] = *(const bf16x8*)&ks[((kf * 2 + f) * 64 + ln) * 8];

    // ---- S^T = K Q^T : 16 MFMA ----
    f32x4 sa[2][2];  // [f][qfl]
#pragma unroll
    for (int f = 0; f < 2; ++f)
#pragma unroll
      for (int qfl = 0; qfl < 2; ++qfl) sa[f][qfl] = (f32x4){0.f, 0.f, 0.f, 0.f};
#pragma unroll
    for (int kf = 0; kf < 4; ++kf)
#pragma unroll
      for (int f = 0; f < 2; ++f) {
        sa[f][0] = __builtin_amdgcn_mfma_f32_16x16x32_bf16(kA[kf][f], qf[0][kf], sa[f][0], 0, 0, 0);
        sa[f][1] = __builtin_amdgcn_mfma_f32_16x16x32_bf16(kA[kf][f], qf[1][kf], sa[f][1], 0, 0, 0);
      }

    // ---- mask + online softmax per qfl (per-lane state, q-row = lc) ----
#pragma unroll
    for (int qfl = 0; qfl < 2; ++qfl) {
#pragma unroll
      for (int r = 0; r < 4; ++r) {
        sa[0][qfl][r] = mk0[r] ? sa[0][qfl][r] : NEGV;
        sa[1][qfl][r] = mk1[r] ? sa[1][qfl][r] : NEGV;
      }
      float rm = fmaxf(fmaxf(fmaxf(sa[0][qfl][0], sa[0][qfl][1]), fmaxf(sa[0][qfl][2], sa[0][qfl][3])),
                       fmaxf(fmaxf(sa[1][qfl][0], sa[1][qfl][1]), fmaxf(sa[1][qfl][2], sa[1][qfl][3])));
      rm = fmaxf(rm, __shfl_xor(rm, 16, 64));
      rm = fmaxf(rm, __shfl_xor(rm, 32, 64));
      const float mn = fmaxf(mi[qfl], rm);
      const float alpha = __builtin_amdgcn_exp2f(mi[qfl] - mn);
      mi[qfl] = mn;
      float rs = 0.f;
#pragma unroll
      for (int f = 0; f < 2; ++f)
#pragma unroll
        for (int r = 0; r < 4; ++r) {
          float p = __builtin_amdgcn_exp2f(sa[f][qfl][r] - mn);
          sa[f][qfl][r] = p;
          rs += p;
        }
      rs += __shfl_xor(rs, 16, 64);
      rs += __shfl_xor(rs, 32, 64);
      li[qfl] = li[qfl] * alpha + rs;

      // P write: row = q-row lc, cols = key-in-slice f*16+qd*4+{r,r+1} (bf16x2)
      __bf16* sp = (qfl == 0) ? sP0 : sP1;
#pragma unroll
      for (int f = 0; f < 2; ++f)
#pragma unroll
        for (int r2 = 0; r2 < 2; ++r2) {
          bf16x2 pp;
          pp[0] = (__bf16)sa[f][qfl][r2 * 2];
          pp[1] = (__bf16)sa[f][qfl][r2 * 2 + 1];
          *(bf16x2*)&sp[lc * PPW + f * 16 + qd * 4 + r2 * 2] = pp;
        }

      // O^T rescale
#pragma unroll
      for (int nt = 0; nt < 8; ++nt)
#pragma unroll
        for (int r = 0; r < 4; ++r) oacc[qfl][nt][r] *= alpha;
    }

    // ---- P B-frags (b128, conflict-free) ----
    bf16x8 pf0 = *(const bf16x8*)&sP0[lc * PPW + qd * 8];
    bf16x8 pf1 = *(const bf16x8*)&sP1[lc * PPW + qd * 8];

    // ---- O^T += V^T P^T : 8 coalesced V loads, 16 MFMA ----
#pragma unroll
    for (int nt = 0; nt < 8; ++nt) {
      bf16x8 vA = *(const bf16x8*)&vs[(nt * 64 + ln) * 8];
      oacc[0][nt] = __builtin_amdgcn_mfma_f32_16x16x32_bf16(vA, pf0, oacc[0][nt], 0, 0, 0);
      oacc[1][nt] = __builtin_amdgcn_mfma_f32_16x16x32_bf16(vA, pf1, oacc[1][nt], 0, 0, 0);
    }
  }

  // ---- end merge: 4 kv-slices per q-group, pair-tree (3,2)(1,0)(2,0) ----
  auto publish = [&]() {
#pragma unroll
    for (int qfl = 0; qfl < 2; ++qfl) {
#pragma unroll
      for (int nt = 0; nt < 8; ++nt)
        mO[((qg * 2 + qfl) * 8 + nt) * 64 + ln] = oacc[qfl][nt];
      if (qd == 0) {
        sml[((qg * 2 + qfl) * 16 + lc) * 2] = mi[qfl];
        sml[((qg * 2 + qfl) * 16 + lc) * 2 + 1] = li[qfl];
      }
    }
  };
  auto absorb = [&]() {
#pragma unroll
    for (int qfl = 0; qfl < 2; ++qfl) {
      const float m2 = sml[((qg * 2 + qfl) * 16 + lc) * 2];
      const float l2 = sml[((qg * 2 + qfl) * 16 + lc) * 2 + 1];
      const float M = fmaxf(mi[qfl], m2);
      const float w1 = __builtin_amdgcn_exp2f(mi[qfl] - M);
      const float w2 = __builtin_amdgcn_exp2f(m2 - M);
      mi[qfl] = M;
      li[qfl] = w1 * li[qfl] + w2 * l2;
#pragma unroll
      for (int nt = 0; nt < 8; ++nt) {
        f32x4 o2 = mO[((qg * 2 + qfl) * 8 + nt) * 64 + ln];
#pragma unroll
        for (int r = 0; r < 4; ++r)
          oacc[qfl][nt][r] = w1 * oacc[qfl][nt][r] + w2 * o2[r];
      }
    }
  };

  __syncthreads();                    // B0: all waves done with sP region
  if (sl == 3) publish();
  __syncthreads();
  if (sl == 2) absorb();
  __syncthreads();
  if (sl == 1) publish();
  __syncthreads();
  if (sl == 0) absorb();
  __syncthreads();
  if (sl == 2) publish();
  __syncthreads();
  if (sl == 0) {
    absorb();
#pragma unroll
    for (int qfl = 0; qfl < 2; ++qfl) {
      const float inv = 1.0f / li[qfl];
      float* orow = outg + ((size_t)(b * QL + q0 + qg * 32 + qfl * 16 + lc)) * DH;
#pragma unroll
      for (int nt = 0; nt < 8; ++nt) {
        f32x4 res;
#pragma unroll
        for (int r = 0; r < 4; ++r) res[r] = oacc[qfl][nt][r] * inv;
        *(f32x4*)&orow[nt * 16 + qd * 4] = res;
      }
    }
  }
}

// ---------------------------------------------------------------------------
// Fallback single-pass kernel (R2, proven) — used only if ws is too small.
// ---------------------------------------------------------------------------
#define KT 64
#define KPITCH 136
#define VPITCH 72
#define PPITCH 72
typedef __bf16 bf16x4 __attribute__((ext_vector_type(4)));

__global__ __launch_bounds__(256, 1) void fattn_mono(
    const float* __restrict__ qgp, const float* __restrict__ kg,
    const float* __restrict__ vg, const int* __restrict__ maskg,
    float* __restrict__ outg) {
  __shared__ __bf16 sK[KT][KPITCH];
  __shared__ __bf16 sVT[DH][VPITCH];
  __shared__ __bf16 sP[4][16][PPITCH];

  const int tid = threadIdx.x;
  const int wv = tid >> 6, ln = tid & 63;
  const int qd = ln >> 4, lc = ln & 15;
  const int bid = blockIdx.x;
  const int b = bid >> 5;
  const int q0 = (bid & 31) << 6;
  const int qw = q0 + (wv << 4);

  bf16x8 qf[4];
  {
    const float* qr = qgp + ((size_t)(b * QL + qw + lc)) * DH + qd * 8;
#pragma unroll
    for (int kf = 0; kf < 4; ++kf) {
      f32x4 a = *(const f32x4*)(qr + kf * 32);
      f32x4 c = *(const f32x4*)(qr + kf * 32 + 4);
      bf16x8 t;
      t[0]=(__bf16)(a[0]*QSC); t[1]=(__bf16)(a[1]*QSC); t[2]=(__bf16)(a[2]*QSC); t[3]=(__bf16)(a[3]*QSC);
      t[4]=(__bf16)(c[0]*QSC); t[5]=(__bf16)(c[1]*QSC); t[6]=(__bf16)(c[2]*QSC); t[7]=(__bf16)(c[3]*QSC);
      qf[kf] = t;
    }
  }

  const float* kb = kg + (size_t)b * KLEN * DH;
  const float* vb = vg + (size_t)b * KLEN * DH;
  const int* mrow = maskg + b * KLEN;

  f32x4 kreg[8], va[4], vbr[4];

  auto load_tile = [&](int t) {
    const float* kt = kb + ((size_t)t * KT) * DH;
#pragma unroll
    for (int it = 0; it < 8; ++it) {
      int f = it * 256 + tid;
      kreg[it] = *(const f32x4*)(kt + (size_t)(f >> 5) * DH + (f & 31) * 4);
    }
    const float* vt = vb + ((size_t)t * KT) * DH;
#pragma unroll
    for (int it = 0; it < 4; ++it) {
      int u = it * 256 + tid;
      int m = u & 31, dc = (u >> 5) * 4;
      va[it]  = *(const f32x4*)(vt + (size_t)(2 * m) * DH + dc);
      vbr[it] = *(const f32x4*)(vt + (size_t)(2 * m + 1) * DH + dc);
    }
  };
  auto store_tile = [&]() {
#pragma unroll
    for (int it = 0; it < 8; ++it) {
      int f = it * 256 + tid;
      bf16x4 w;
      w[0]=(__bf16)kreg[it][0]; w[1]=(__bf16)kreg[it][1];
      w[2]=(__bf16)kreg[it][2]; w[3]=(__bf16)kreg[it][3];
      *(bf16x4*)&sK[f >> 5][(f & 31) * 4] = w;
    }
#pragma unroll
    for (int it = 0; it < 4; ++it) {
      int u = it * 256 + tid;
      int m = u & 31, dc = (u >> 5) * 4;
#pragma unroll
      for (int j = 0; j < 4; ++j) {
        bf16x2 p2;
        p2[0] = (__bf16)va[it][j];
        p2[1] = (__bf16)vbr[it][j];
        *(bf16x2*)&sVT[dc + j][2 * m] = p2;
      }
    }
  };

  f32x4 oacc[8];
#pragma unroll
  for (int i = 0; i < 8; ++i) oacc[i] = (f32x4){0.f, 0.f, 0.f, 0.f};
  float mi[4] = {-INFINITY, -INFINITY, -INFINITY, -INFINITY};
  float li[4] = {0.f, 0.f, 0.f, 0.f};

  load_tile(0); store_tile(); __syncthreads();

  for (int t = 0; t < (KLEN / KT); ++t) {
    const bool more = (t + 1 < (KLEN / KT));
    if (more) load_tile(t + 1);

    f32x4 sa[4];
#pragma unroll
    for (int f = 0; f < 4; ++f) sa[f] = (f32x4){0.f, 0.f, 0.f, 0.f};
#pragma unroll
    for (int kf = 0; kf < 4; ++kf)
#pragma unroll
      for (int f = 0; f < 4; ++f) {
        bf16x8 bk = *(const bf16x8*)&sK[f * 16 + lc][kf * 32 + qd * 8];
        sa[f] = __builtin_amdgcn_mfma_f32_16x16x32_bf16(qf[kf], bk, sa[f], 0, 0, 0);
      }

    const int kv0 = t * KT;
#pragma unroll
    for (int f = 0; f < 4; ++f) {
      const bool keep = mrow[kv0 + f * 16 + lc] != 0;
#pragma unroll
      for (int r = 0; r < 4; ++r) sa[f][r] = keep ? sa[f][r] : NEGV;
    }

    float rm[4], alpha[4], rs[4];
#pragma unroll
    for (int r = 0; r < 4; ++r)
      rm[r] = fmaxf(fmaxf(sa[0][r], sa[1][r]), fmaxf(sa[2][r], sa[3][r]));
#pragma unroll
    for (int sh = 0; sh < 4; ++sh) {
      const int off = 1 << sh;
#pragma unroll
      for (int r = 0; r < 4; ++r) rm[r] = fmaxf(rm[r], __shfl_xor(rm[r], off, 64));
    }
#pragma unroll
    for (int r = 0; r < 4; ++r) {
      float mn = fmaxf(mi[r], rm[r]);
      alpha[r] = __builtin_amdgcn_exp2f(mi[r] - mn);
      mi[r] = mn; rs[r] = 0.f;
    }
#pragma unroll
    for (int f = 0; f < 4; ++f)
#pragma unroll
      for (int r = 0; r < 4; ++r) {
        float p = __builtin_amdgcn_exp2f(sa[f][r] - mi[r]);
        sa[f][r] = p; rs[r] += p;
      }
#pragma unroll
    for (int sh = 0; sh < 4; ++sh) {
      const int off = 1 << sh;
#pragma unroll
      for (int r = 0; r < 4; ++r) rs[r] += __shfl_xor(rs[r], off, 64);
    }
#pragma unroll
    for (int r = 0; r < 4; ++r) li[r] = li[r] * alpha[r] + rs[r];

#pragma unroll
    for (int f = 0; f < 4; ++f)
#pragma unroll
      for (int r = 0; r < 4; ++r)
        sP[wv][qd * 4 + r][f * 16 + lc] = (__bf16)sa[f][r];
#pragma unroll
    for (int nt = 0; nt < 8; ++nt)
#pragma unroll
      for (int r = 0; r < 4; ++r) oacc[nt][r] *= alpha[r];

#pragma unroll
    for (int kp = 0; kp < 2; ++kp) {
      bf16x8 ap = *(const bf16x8*)&sP[wv][lc][kp * 32 + qd * 8];
#pragma unroll
      for (int nt = 0; nt < 8; ++nt) {
        bf16x8 bv = *(const bf16x8*)&sVT[nt * 16 + lc][kp * 32 + qd * 8];
        oacc[nt] = __builtin_amdgcn_mfma_f32_16x16x32_bf16(ap, bv, oacc[nt], 0, 0, 0);
      }
    }

    __syncthreads();
    if (more) store_tile();
    __syncthreads();
  }

  float inv[4];
#pragma unroll
  for (int r = 0; r < 4; ++r) inv[r] = 1.0f / li[r];
  float* orow = outg + ((size_t)(b * QL + qw)) * DH;
#pragma unroll
  for (int nt = 0; nt < 8; ++nt)
#pragma unroll
    for (int r = 0; r < 4; ++r)
      orow[(size_t)(qd * 4 + r) * DH + nt * 16 + lc] = oacc[nt][r] * inv[r];
}

extern "C" void kernel_launch(void* const* d_in, const int* in_sizes, int n_in,
                              void* d_out, int out_size, void* d_ws, size_t ws_size,
                              hipStream_t stream) {
  (void)in_sizes; (void)n_in; (void)out_size;
  const float* q = (const float*)d_in[0];
  const float* k = (const float*)d_in[1];
  const float* v = (const float*)d_in[2];
  const int* mask = (const int*)d_in[3];
  float* out = (float*)d_out;

  const size_t kv_elems = (size_t)BZ * KLEN * DH;        // per tensor
  if (ws_size >= 2 * kv_elems * sizeof(__bf16)) {
    __bf16* khat = (__bf16*)d_ws;
    __bf16* vhat = khat + kv_elems;
    prep_kv<<<dim3(1024), dim3(256), 0, stream>>>(k, v, khat, vhat);
    fattn3<<<dim3(256), dim3(512), 0, stream>>>(khat, vhat, q, mask, out);
  } else {
    fattn_mono<<<dim3(BZ * (QL / 64)), dim3(256), 0, stream>>>(q, k, v, mask, out);
  }
}